// Round 1
// baseline (136.646 us; speedup 1.0000x reference)
//
#include <hip/hip_runtime.h>

#define X_SLAB   1048576            // 32^4
#define PAD_D    34
#define PAD_S3   34                 // stride d3
#define PAD_S2   (34*34)            // 1156
#define PAD_S1   (34*34*34)         // 39304
#define PAD_SLAB (34*34*34*34)      // 1336336
#define TAB_ELEMS (4*81*8)          // 2592

// ---------------------------------------------------------------------------
// Weight table: tab[t][p2][p3][p4][p5][n], n = (s1*2+s2)*2 + branch
// branch0: w[a',b',p2,p3,p4,p5], branch1: w[b',a',p4,p5,p2,p3]
// with a' = t1-s1+1, b' = t2-s2+1   (always in [0,2] since s,t in {0,1})
// ---------------------------------------------------------------------------
__global__ void build_wtab(const float* __restrict__ w, float* __restrict__ tab) {
    int idx = blockIdx.x * blockDim.x + threadIdx.x;
    if (idx >= TAB_ELEMS) return;
    int n  = idx & 7;
    int r  = idx >> 3;
    int p5 = r % 3; r /= 3;
    int p4 = r % 3; r /= 3;
    int p3 = r % 3; r /= 3;
    int p2 = r % 3; r /= 3;
    int t  = r;                       // 0..3  (t1*2+t2)
    int t1 = t >> 1, t2 = t & 1;
    int br = n & 1;
    int s  = n >> 1;                  // s1*2+s2
    int s1 = s >> 1, s2 = s & 1;
    int a = t1 - s1 + 1;
    int b = t2 - s2 + 1;
    int widx = (br == 0)
        ? (a*243 + b*81 + p2*27 + p3*9 + p4*3 + p5)
        : (b*243 + a*81 + p4*27 + p5*9 + p2*3 + p3);
    tab[idx] = w[widx];
}

// ---------------------------------------------------------------------------
// Padded relu copy: rp[t][j1][j2][j3][j4] (j in [0,34)) = relu(x[t][j-1...]),
// zero outside. rp[j] == r[j-1] so gathers use e+p directly (p in 0..2).
// ---------------------------------------------------------------------------
__global__ void pad_relu(const float* __restrict__ x, float* __restrict__ rp) {
    unsigned gid = blockIdx.x * blockDim.x + threadIdx.x;
    const unsigned total = 4u * PAD_SLAB;
    if (gid >= total) return;
    unsigned q = gid;
    int j4 = q % 34; q /= 34;
    int j3 = q % 34; q /= 34;
    int j2 = q % 34; q /= 34;
    int j1 = q % 34; q /= 34;
    int t  = q;
    float v = 0.f;
    if (j1 >= 1 && j1 <= 32 && j2 >= 1 && j2 <= 32 &&
        j3 >= 1 && j3 <= 32 && j4 >= 1 && j4 <= 32) {
        v = x[(size_t)t*X_SLAB + (j1-1)*32768 + (j2-1)*1024 + (j3-1)*32 + (j4-1)];
        v = fmaxf(v, 0.f);
    }
    rp[gid] = v;
}

// ---------------------------------------------------------------------------
// Main kernel: one thread per output point (e1,e2,e3,e4).
// 8 accumulators = 4 (s1,s2) combos x 2 branches, sharing all 324 gathers.
// ---------------------------------------------------------------------------
template<bool PADDED>
__global__ __launch_bounds__(256)
void conv_main(const float* __restrict__ x,
               const float* __restrict__ src,   // rpad (padded) or x (direct)
               const float* __restrict__ tab,
               float* __restrict__ out) {
    const int e4 = threadIdx.x;                    // 0..31
    const int e3 = blockIdx.x * 8 + threadIdx.y;   // 0..31
    const int e2 = blockIdx.y;
    const int e1 = blockIdx.z;

    float acc[8];
    #pragma unroll
    for (int n = 0; n < 8; ++n) acc[n] = 0.f;

    #pragma unroll 1
    for (int t = 0; t < 4; ++t) {
        const float* st  = src + (size_t)t * (PADDED ? PAD_SLAB : X_SLAB);
        const float* wt0 = tab + t * 648;          // 81*8 weights per slab
        #pragma unroll
        for (int p2 = 0; p2 < 3; ++p2) {
            #pragma unroll
            for (int p3 = 0; p3 < 3; ++p3) {
                const float* wt = wt0 + (p2*3 + p3) * 72;
                if (PADDED) {
                    const float* base = st + ((e1+p2)*PAD_S1 + (e2+p3)*PAD_S2
                                              + e3*PAD_S3 + e4);
                    #pragma unroll
                    for (int p4 = 0; p4 < 3; ++p4) {
                        #pragma unroll
                        for (int p5 = 0; p5 < 3; ++p5) {
                            float v = base[p4*PAD_S3 + p5];
                            const float* w8 = wt + (p4*3 + p5)*8;
                            #pragma unroll
                            for (int n = 0; n < 8; ++n)
                                acc[n] = fmaf(w8[n], v, acc[n]);
                        }
                    }
                } else {
                    int i1 = e1 + p2 - 1, i2 = e2 + p3 - 1;
                    bool v12 = ((unsigned)i1 < 32u) && ((unsigned)i2 < 32u);
                    const float* base = st + (i1*32768 + i2*1024 + (e3-1)*32 + (e4-1));
                    #pragma unroll
                    for (int p4 = 0; p4 < 3; ++p4) {
                        int i3 = e3 + p4 - 1;
                        bool v3 = v12 && ((unsigned)i3 < 32u);
                        #pragma unroll
                        for (int p5 = 0; p5 < 3; ++p5) {
                            int i4 = e4 + p5 - 1;
                            bool ok = v3 && ((unsigned)i4 < 32u);
                            float v = ok ? fmaxf(base[p4*32 + p5], 0.f) : 0.f;
                            const float* w8 = wt + (p4*3 + p5)*8;
                            #pragma unroll
                            for (int n = 0; n < 8; ++n)
                                acc[n] = fmaf(w8[n], v, acc[n]);
                        }
                    }
                }
            }
        }
    }

    const size_t eflat = (size_t)e1*32768 + e2*1024 + e3*32 + e4;
    float res = 0.f;
    #pragma unroll
    for (int i = 0; i < 4; ++i) {        // i = s1*2+s2
        float xv = x[(size_t)i * X_SLAB + eflat];
        float m  = (xv != 0.f) ? 1.f : 0.f;
        float s0 = 1.f / (1.f + __expf(-acc[2*i]));
        float s1 = 1.f / (1.f + __expf(-acc[2*i+1]));
        res += m * (s0 + s1);
    }
    out[eflat] = res;
}

// ---------------------------------------------------------------------------
extern "C" void kernel_launch(void* const* d_in, const int* in_sizes, int n_in,
                              void* d_out, int out_size, void* d_ws, size_t ws_size,
                              hipStream_t stream) {
    const float* x = (const float*)d_in[0];    // (1,2,2,32,32,32,32) fp32
    const float* w = (const float*)d_in[1];    // (729,) fp32
    float* out = (float*)d_out;                // (1,32,32,32,32) fp32

    float* tab  = (float*)d_ws;                // 2592 floats
    float* rpad = (float*)d_ws + 4096;         // 4*34^4 floats, 16KB-aligned

    build_wtab<<<dim3((TAB_ELEMS + 255)/256), dim3(256), 0, stream>>>(w, tab);

    const size_t need_padded = (4096 + 4*(size_t)PAD_SLAB) * sizeof(float);
    dim3 blk(32, 8, 1), grd(4, 32, 32);
    if (ws_size >= need_padded) {
        unsigned total = 4u * PAD_SLAB;
        pad_relu<<<dim3((total + 255)/256), dim3(256), 0, stream>>>(x, rpad);
        conv_main<true><<<grd, blk, 0, stream>>>(x, rpad, tab, out);
    } else {
        conv_main<false><<<grd, blk, 0, stream>>>(x, x, tab, out);
    }
}

// Round 2
// 114.506 us; speedup vs baseline: 1.1934x; 1.1934x over previous
//
#include <hip/hip_runtime.h>

typedef _Float16 h2 __attribute__((ext_vector_type(2)));

#define X_SLAB   1048576            // 32^4
#define PAD_S3   34
#define PAD_S2   (34*34)            // 1156
#define PAD_S1   (34*34*34)         // 39304
#define PAD_SLAB (34*34*34*34)      // 1336336
#define TAB2_ELEMS (2*81*8)         // 1296  (half2 entries)
#define TAB_ELEMS  (4*81*8)         // 2592  (fp32 fallback)

// ---------------------------------------------------------------------------
// prep: (a) t-interleaved padded relu f16 array
//           rp2[tp][j1][j2][j3][j4] = { relu(x[2tp]), relu(x[2tp+1]) } at j-1
//       (b) block 0 also builds the half2 weight table
//           tab2[tp][p2][p3][p4][p5][n] = { w_t(2tp,n,...), w_t(2tp+1,n,...) }
//           n = (s1*2+s2)*2 + branch
//           branch0: w[a',b',p2,p3,p4,p5], branch1: w[b',a',p4,p5,p2,p3]
//           a' = t1-s1+1, b' = t2-s2+1
// ---------------------------------------------------------------------------
__global__ __launch_bounds__(256)
void prep(const float* __restrict__ x, const float* __restrict__ w,
          h2* __restrict__ rp2, h2* __restrict__ tab2) {
    unsigned gid = blockIdx.x * 256 + threadIdx.x;
    const unsigned total = 2u * PAD_SLAB;
    if (gid < total) {
        unsigned q = gid;
        int j4 = q % 34; q /= 34;
        int j3 = q % 34; q /= 34;
        int j2 = q % 34; q /= 34;
        int j1 = q % 34; q /= 34;
        int tp = q;
        float a = 0.f, b = 0.f;
        if (j1 >= 1 && j1 <= 32 && j2 >= 1 && j2 <= 32 &&
            j3 >= 1 && j3 <= 32 && j4 >= 1 && j4 <= 32) {
            size_t off = (size_t)(j1-1)*32768 + (j2-1)*1024 + (j3-1)*32 + (j4-1);
            a = fmaxf(x[(size_t)(2*tp  )*X_SLAB + off], 0.f);
            b = fmaxf(x[(size_t)(2*tp+1)*X_SLAB + off], 0.f);
        }
        h2 hv; hv.x = (_Float16)a; hv.y = (_Float16)b;
        rp2[gid] = hv;
    }
    if (blockIdx.x == 0) {
        for (int idx = threadIdx.x; idx < TAB2_ELEMS; idx += 256) {
            int n  = idx & 7;
            int r  = idx >> 3;
            int p5 = r % 3; r /= 3;
            int p4 = r % 3; r /= 3;
            int p3 = r % 3; r /= 3;
            int p2 = r % 3; r /= 3;
            int tp = r;
            int br = n & 1, s = n >> 1, s1 = s >> 1, s2 = s & 1;
            float vv[2];
            #pragma unroll
            for (int dt = 0; dt < 2; ++dt) {
                int t = 2*tp + dt, t1 = t >> 1, t2 = t & 1;
                int a2 = t1 - s1 + 1, b2 = t2 - s2 + 1;
                int widx = (br == 0)
                    ? (a2*243 + b2*81 + p2*27 + p3*9 + p4*3 + p5)
                    : (b2*243 + a2*81 + p4*27 + p5*9 + p2*3 + p3);
                vv[dt] = w[widx];
            }
            h2 hw; hw.x = (_Float16)vv[0]; hw.y = (_Float16)vv[1];
            tab2[idx] = hw;
        }
    }
}

// ---------------------------------------------------------------------------
// Main kernel: one thread per output point. 8 accumulators (4 s-combos x 2
// branches) share every gathered half2; dot2 does 2 t-slabs per instruction.
// ---------------------------------------------------------------------------
__global__ __launch_bounds__(256)
void conv_dot2(const float* __restrict__ x,
               const h2* __restrict__ rp2,
               const h2* __restrict__ tab2,
               float* __restrict__ out) {
    const int e4 = threadIdx.x;                    // 0..31
    const int e3 = blockIdx.x * 8 + threadIdx.y;   // 0..31
    const int e2 = blockIdx.y;
    const int e1 = blockIdx.z;

    float acc[8];
    #pragma unroll
    for (int n = 0; n < 8; ++n) acc[n] = 0.f;

    #pragma unroll 1
    for (int tp = 0; tp < 2; ++tp) {
        const h2* st  = rp2 + (size_t)tp * PAD_SLAB;
        const h2* wt0 = tab2 + tp * 648;
        #pragma unroll
        for (int p2 = 0; p2 < 3; ++p2) {
            #pragma unroll
            for (int p3 = 0; p3 < 3; ++p3) {
                const h2* base = st + ((e1+p2)*PAD_S1 + (e2+p3)*PAD_S2
                                       + e3*PAD_S3 + e4);
                const h2* wt = wt0 + (p2*3 + p3) * 72;
                #pragma unroll
                for (int p4 = 0; p4 < 3; ++p4) {
                    #pragma unroll
                    for (int p5 = 0; p5 < 3; ++p5) {
                        h2 v = base[p4*PAD_S3 + p5];
                        const h2* w8 = wt + (p4*3 + p5)*8;
                        #pragma unroll
                        for (int n = 0; n < 8; ++n)
                            acc[n] = __builtin_amdgcn_fdot2(v, w8[n], acc[n], false);
                    }
                }
            }
        }
    }

    const size_t eflat = (size_t)e1*32768 + e2*1024 + e3*32 + e4;
    float res = 0.f;
    #pragma unroll
    for (int i = 0; i < 4; ++i) {        // i = s1*2+s2
        float xv = x[(size_t)i * X_SLAB + eflat];
        float s0 = __builtin_amdgcn_rcpf(1.f + __expf(-acc[2*i]));
        float s1 = __builtin_amdgcn_rcpf(1.f + __expf(-acc[2*i+1]));
        float m  = (xv != 0.f) ? 1.f : 0.f;
        res = fmaf(m, s0 + s1, res);
    }
    out[eflat] = res;
}

// ---------------------------------------------------------------------------
// fp32 fallback (no workspace for rp2): direct reads of x with bounds checks.
// ---------------------------------------------------------------------------
__global__ void build_wtab(const float* __restrict__ w, float* __restrict__ tab) {
    int idx = blockIdx.x * blockDim.x + threadIdx.x;
    if (idx >= TAB_ELEMS) return;
    int n  = idx & 7;
    int r  = idx >> 3;
    int p5 = r % 3; r /= 3;
    int p4 = r % 3; r /= 3;
    int p3 = r % 3; r /= 3;
    int p2 = r % 3; r /= 3;
    int t  = r;
    int t1 = t >> 1, t2 = t & 1;
    int br = n & 1;
    int s  = n >> 1;
    int s1 = s >> 1, s2 = s & 1;
    int a = t1 - s1 + 1;
    int b = t2 - s2 + 1;
    int widx = (br == 0)
        ? (a*243 + b*81 + p2*27 + p3*9 + p4*3 + p5)
        : (b*243 + a*81 + p4*27 + p5*9 + p2*3 + p3);
    tab[idx] = w[widx];
}

__global__ __launch_bounds__(256)
void conv_fp32(const float* __restrict__ x,
               const float* __restrict__ tab,
               float* __restrict__ out) {
    const int e4 = threadIdx.x;
    const int e3 = blockIdx.x * 8 + threadIdx.y;
    const int e2 = blockIdx.y;
    const int e1 = blockIdx.z;

    float acc[8];
    #pragma unroll
    for (int n = 0; n < 8; ++n) acc[n] = 0.f;

    #pragma unroll 1
    for (int t = 0; t < 4; ++t) {
        const float* st  = x + (size_t)t * X_SLAB;
        const float* wt0 = tab + t * 648;
        #pragma unroll
        for (int p2 = 0; p2 < 3; ++p2) {
            #pragma unroll
            for (int p3 = 0; p3 < 3; ++p3) {
                int i1 = e1 + p2 - 1, i2 = e2 + p3 - 1;
                bool v12 = ((unsigned)i1 < 32u) && ((unsigned)i2 < 32u);
                const float* base = st + (i1*32768 + i2*1024 + (e3-1)*32 + (e4-1));
                const float* wt = wt0 + (p2*3 + p3) * 72;
                #pragma unroll
                for (int p4 = 0; p4 < 3; ++p4) {
                    int i3 = e3 + p4 - 1;
                    bool v3 = v12 && ((unsigned)i3 < 32u);
                    #pragma unroll
                    for (int p5 = 0; p5 < 3; ++p5) {
                        int i4 = e4 + p5 - 1;
                        bool ok = v3 && ((unsigned)i4 < 32u);
                        float v = ok ? fmaxf(base[p4*32 + p5], 0.f) : 0.f;
                        const float* w8 = wt + (p4*3 + p5)*8;
                        #pragma unroll
                        for (int n = 0; n < 8; ++n)
                            acc[n] = fmaf(w8[n], v, acc[n]);
                    }
                }
            }
        }
    }

    const size_t eflat = (size_t)e1*32768 + e2*1024 + e3*32 + e4;
    float res = 0.f;
    #pragma unroll
    for (int i = 0; i < 4; ++i) {
        float xv = x[(size_t)i * X_SLAB + eflat];
        float s0 = __builtin_amdgcn_rcpf(1.f + __expf(-acc[2*i]));
        float s1 = __builtin_amdgcn_rcpf(1.f + __expf(-acc[2*i+1]));
        float m  = (xv != 0.f) ? 1.f : 0.f;
        res = fmaf(m, s0 + s1, res);
    }
    out[eflat] = res;
}

// ---------------------------------------------------------------------------
extern "C" void kernel_launch(void* const* d_in, const int* in_sizes, int n_in,
                              void* d_out, int out_size, void* d_ws, size_t ws_size,
                              hipStream_t stream) {
    const float* x = (const float*)d_in[0];    // (1,2,2,32,32,32,32) fp32
    const float* w = (const float*)d_in[1];    // (729,) fp32
    float* out = (float*)d_out;                // (1,32,32,32,32) fp32

    const size_t need = 16384 + (size_t)2 * PAD_SLAB * sizeof(h2);
    dim3 blk(32, 8, 1), grd(4, 32, 32);

    if (ws_size >= need) {
        h2* tab2 = (h2*)d_ws;                              // 1296 * 4B
        h2* rp2  = (h2*)((char*)d_ws + 16384);             // 2*34^4 * 4B
        unsigned total = 2u * PAD_SLAB;
        prep<<<dim3((total + 255)/256), dim3(256), 0, stream>>>(x, w, rp2, tab2);
        conv_dot2<<<grd, blk, 0, stream>>>(x, rp2, tab2, out);
    } else {
        float* tab = (float*)d_ws;                         // 2592 * 4B
        build_wtab<<<dim3((TAB_ELEMS + 255)/256), dim3(256), 0, stream>>>(w, tab);
        conv_fp32<<<grd, blk, 0, stream>>>(x, tab, out);
    }
}

// Round 3
// 112.301 us; speedup vs baseline: 1.2168x; 1.0196x over previous
//
#include <hip/hip_runtime.h>

typedef _Float16 h2 __attribute__((ext_vector_type(2)));
typedef _Float16 h4 __attribute__((ext_vector_type(4)));
typedef float f4 __attribute__((ext_vector_type(4)));

#define X_SLAB   1048576            // 32^4
#define PAD_S3   34
#define PAD_S2   (34*34)            // 1156
#define PAD_S1   (34*34*34)         // 39304
#define PAD_SLAB (34*34*34*34)      // 1336336
#define TAB2_ELEMS (2*81*8)         // 1296  (half2 entries)
#define TAB_ELEMS  (4*81*8)         // 2592  (fp32 fallback)

// ---------------------------------------------------------------------------
// prep: (a) t-interleaved padded relu f16 array
//           rp2[tp][j1][j2][j3][j4] = { relu(x[2tp]), relu(x[2tp+1]) } at j-1
//       (b) block 0 also builds the half2 weight table
//           tab2[tp][p2][p3][p4][p5][n] = { w_t(2tp,n,...), w_t(2tp+1,n,...) }
//           n = (s1*2+s2)*2 + branch
//           branch0: w[a',b',p2,p3,p4,p5], branch1: w[b',a',p4,p5,p2,p3]
//           a' = t1-s1+1, b' = t2-s2+1
// ---------------------------------------------------------------------------
__global__ __launch_bounds__(256)
void prep(const float* __restrict__ x, const float* __restrict__ w,
          h2* __restrict__ rp2, h2* __restrict__ tab2) {
    unsigned gid = blockIdx.x * 256 + threadIdx.x;
    const unsigned total = 2u * PAD_SLAB;
    if (gid < total) {
        unsigned q = gid;
        int j4 = q % 34; q /= 34;
        int j3 = q % 34; q /= 34;
        int j2 = q % 34; q /= 34;
        int j1 = q % 34; q /= 34;
        int tp = q;
        float a = 0.f, b = 0.f;
        if (j1 >= 1 && j1 <= 32 && j2 >= 1 && j2 <= 32 &&
            j3 >= 1 && j3 <= 32 && j4 >= 1 && j4 <= 32) {
            size_t off = (size_t)(j1-1)*32768 + (j2-1)*1024 + (j3-1)*32 + (j4-1);
            a = fmaxf(x[(size_t)(2*tp  )*X_SLAB + off], 0.f);
            b = fmaxf(x[(size_t)(2*tp+1)*X_SLAB + off], 0.f);
        }
        h2 hv; hv.x = (_Float16)a; hv.y = (_Float16)b;
        rp2[gid] = hv;
    }
    if (blockIdx.x == 0) {
        for (int idx = threadIdx.x; idx < TAB2_ELEMS; idx += 256) {
            int n  = idx & 7;
            int r  = idx >> 3;
            int p5 = r % 3; r /= 3;
            int p4 = r % 3; r /= 3;
            int p3 = r % 3; r /= 3;
            int p2 = r % 3; r /= 3;
            int tp = r;
            int br = n & 1, s = n >> 1, s1 = s >> 1, s2 = s & 1;
            float vv[2];
            #pragma unroll
            for (int dt = 0; dt < 2; ++dt) {
                int t = 2*tp + dt, t1 = t >> 1, t2 = t & 1;
                int a2 = t1 - s1 + 1, b2 = t2 - s2 + 1;
                int widx = (br == 0)
                    ? (a2*243 + b2*81 + p2*27 + p3*9 + p4*3 + p5)
                    : (b2*243 + a2*81 + p4*27 + p5*9 + p2*3 + p3);
                vv[dt] = w[widx];
            }
            h2 hw; hw.x = (_Float16)vv[0]; hw.y = (_Float16)vv[1];
            tab2[idx] = hw;
        }
    }
}

// ---------------------------------------------------------------------------
// Main kernel: each thread computes FOUR consecutive e4 points.
// Per (tp,p2,p3,p4) row: three 8B loads give the 6-h2 sliding window shared
// by all 4 points x 3 p5 taps x 8 accumulators.
// Block (8,32): tx -> e4 block (E4 = 4*tx), ty -> e3. Grid (32,32) = (e2,e1).
// ---------------------------------------------------------------------------
__global__ __launch_bounds__(256)
void conv_dot2(const float* __restrict__ x,
               const h2* __restrict__ rp2,
               const h2* __restrict__ tab2,
               float* __restrict__ out) {
    const int E4 = threadIdx.x * 4;                // 0,4,...,28
    const int e3 = threadIdx.y;                    // 0..31
    const int e2 = blockIdx.x;
    const int e1 = blockIdx.y;

    float acc[4][8];                               // [q][n]
    #pragma unroll
    for (int q = 0; q < 4; ++q)
        #pragma unroll
        for (int n = 0; n < 8; ++n) acc[q][n] = 0.f;

    #pragma unroll 1
    for (int tp = 0; tp < 2; ++tp) {
        #pragma unroll 1
        for (int p2 = 0; p2 < 3; ++p2) {
            #pragma unroll 1
            for (int p3 = 0; p3 < 3; ++p3) {
                const h2* bp = rp2 + (size_t)tp*PAD_SLAB + (e1+p2)*PAD_S1
                             + (e2+p3)*PAD_S2 + e3*PAD_S3 + E4;
                const h2* wt = tab2 + (tp*9 + p2*3 + p3) * 72;
                #pragma unroll
                for (int p4 = 0; p4 < 3; ++p4) {
                    const h4* row = (const h4*)(bp + p4*PAD_S3); // 8B aligned
                    h4 A = row[0];                 // h2 elems E4+0, E4+1
                    h4 B = row[1];                 // E4+2, E4+3
                    h4 C = row[2];                 // E4+4, E4+5
                    h2 v[6];
                    v[0] = __builtin_shufflevector(A, A, 0, 1);
                    v[1] = __builtin_shufflevector(A, A, 2, 3);
                    v[2] = __builtin_shufflevector(B, B, 0, 1);
                    v[3] = __builtin_shufflevector(B, B, 2, 3);
                    v[4] = __builtin_shufflevector(C, C, 0, 1);
                    v[5] = __builtin_shufflevector(C, C, 2, 3);
                    #pragma unroll
                    for (int p5 = 0; p5 < 3; ++p5) {
                        const h2* w8 = wt + (p4*3 + p5)*8;
                        #pragma unroll
                        for (int q = 0; q < 4; ++q) {
                            h2 hv = v[q + p5];
                            #pragma unroll
                            for (int n = 0; n < 8; ++n)
                                acc[q][n] = __builtin_amdgcn_fdot2(hv, w8[n],
                                                                  acc[q][n], false);
                        }
                    }
                }
            }
        }
    }

    const size_t eflat = (size_t)e1*32768 + e2*1024 + e3*32 + E4;
    float res[4] = {0.f, 0.f, 0.f, 0.f};
    #pragma unroll
    for (int i = 0; i < 4; ++i) {                  // i = s1*2+s2
        f4 xv = *(const f4*)(x + (size_t)i*X_SLAB + eflat);   // 16B aligned
        #pragma unroll
        for (int q = 0; q < 4; ++q) {
            float s0 = __builtin_amdgcn_rcpf(1.f + __expf(-acc[q][2*i]));
            float s1 = __builtin_amdgcn_rcpf(1.f + __expf(-acc[q][2*i+1]));
            float m  = (xv[q] != 0.f) ? 1.f : 0.f;
            res[q] = fmaf(m, s0 + s1, res[q]);
        }
    }
    f4 r4; r4.x = res[0]; r4.y = res[1]; r4.z = res[2]; r4.w = res[3];
    *(f4*)(out + eflat) = r4;
}

// ---------------------------------------------------------------------------
// fp32 fallback (no workspace for rp2): direct reads of x with bounds checks.
// ---------------------------------------------------------------------------
__global__ void build_wtab(const float* __restrict__ w, float* __restrict__ tab) {
    int idx = blockIdx.x * blockDim.x + threadIdx.x;
    if (idx >= TAB_ELEMS) return;
    int n  = idx & 7;
    int r  = idx >> 3;
    int p5 = r % 3; r /= 3;
    int p4 = r % 3; r /= 3;
    int p3 = r % 3; r /= 3;
    int p2 = r % 3; r /= 3;
    int t  = r;
    int t1 = t >> 1, t2 = t & 1;
    int br = n & 1;
    int s  = n >> 1;
    int s1 = s >> 1, s2 = s & 1;
    int a = t1 - s1 + 1;
    int b = t2 - s2 + 1;
    int widx = (br == 0)
        ? (a*243 + b*81 + p2*27 + p3*9 + p4*3 + p5)
        : (b*243 + a*81 + p4*27 + p5*9 + p2*3 + p3);
    tab[idx] = w[widx];
}

__global__ __launch_bounds__(256)
void conv_fp32(const float* __restrict__ x,
               const float* __restrict__ tab,
               float* __restrict__ out) {
    const int e4 = threadIdx.x;
    const int e3 = blockIdx.x * 8 + threadIdx.y;
    const int e2 = blockIdx.y;
    const int e1 = blockIdx.z;

    float acc[8];
    #pragma unroll
    for (int n = 0; n < 8; ++n) acc[n] = 0.f;

    #pragma unroll 1
    for (int t = 0; t < 4; ++t) {
        const float* st  = x + (size_t)t * X_SLAB;
        const float* wt0 = tab + t * 648;
        #pragma unroll
        for (int p2 = 0; p2 < 3; ++p2) {
            #pragma unroll
            for (int p3 = 0; p3 < 3; ++p3) {
                int i1 = e1 + p2 - 1, i2 = e2 + p3 - 1;
                bool v12 = ((unsigned)i1 < 32u) && ((unsigned)i2 < 32u);
                const float* base = st + (i1*32768 + i2*1024 + (e3-1)*32 + (e4-1));
                const float* wt = wt0 + (p2*3 + p3) * 72;
                #pragma unroll
                for (int p4 = 0; p4 < 3; ++p4) {
                    int i3 = e3 + p4 - 1;
                    bool v3 = v12 && ((unsigned)i3 < 32u);
                    #pragma unroll
                    for (int p5 = 0; p5 < 3; ++p5) {
                        int i4 = e4 + p5 - 1;
                        bool ok = v3 && ((unsigned)i4 < 32u);
                        float v = ok ? fmaxf(base[p4*32 + p5], 0.f) : 0.f;
                        const float* w8 = wt + (p4*3 + p5)*8;
                        #pragma unroll
                        for (int n = 0; n < 8; ++n)
                            acc[n] = fmaf(w8[n], v, acc[n]);
                    }
                }
            }
        }
    }

    const size_t eflat = (size_t)e1*32768 + e2*1024 + e3*32 + e4;
    float res = 0.f;
    #pragma unroll
    for (int i = 0; i < 4; ++i) {
        float xv = x[(size_t)i * X_SLAB + eflat];
        float s0 = __builtin_amdgcn_rcpf(1.f + __expf(-acc[2*i]));
        float s1 = __builtin_amdgcn_rcpf(1.f + __expf(-acc[2*i+1]));
        float m  = (xv != 0.f) ? 1.f : 0.f;
        res = fmaf(m, s0 + s1, res);
    }
    out[eflat] = res;
}

// ---------------------------------------------------------------------------
extern "C" void kernel_launch(void* const* d_in, const int* in_sizes, int n_in,
                              void* d_out, int out_size, void* d_ws, size_t ws_size,
                              hipStream_t stream) {
    const float* x = (const float*)d_in[0];    // (1,2,2,32,32,32,32) fp32
    const float* w = (const float*)d_in[1];    // (729,) fp32
    float* out = (float*)d_out;                // (1,32,32,32,32) fp32

    const size_t need = 16384 + (size_t)2 * PAD_SLAB * sizeof(h2);

    if (ws_size >= need) {
        h2* tab2 = (h2*)d_ws;                              // 1296 * 4B
        h2* rp2  = (h2*)((char*)d_ws + 16384);             // 2*34^4 * 4B
        unsigned total = 2u * PAD_SLAB;
        prep<<<dim3((total + 255)/256), dim3(256), 0, stream>>>(x, w, rp2, tab2);
        dim3 blk(8, 32, 1), grd(32, 32, 1);
        conv_dot2<<<grd, blk, 0, stream>>>(x, rp2, tab2, out);
    } else {
        float* tab = (float*)d_ws;                         // 2592 * 4B
        build_wtab<<<dim3((TAB_ELEMS + 255)/256), dim3(256), 0, stream>>>(w, tab);
        dim3 blk(32, 8, 1), grd(4, 32, 32);
        conv_fp32<<<grd, blk, 0, stream>>>(x, tab, out);
    }
}